// Round 5
// baseline (106027.722 us; speedup 1.0000x reference)
//
#include <hip/hip_runtime.h>
#include <hip/hip_cooperative_groups.h>
#include <math.h>

#define B_   64
#define U_   1024
#define E_   512
#define D_   640
#define L4_  2560
#define SLOT 40960           // 640*64 floats per h slot
#define RWG  240             // 80 layer-0 WGs + 160 layer-1 WGs
#define GRP  16              // barrier tree: 16 groups x 15 WGs
#define GSZ  15

__device__ __forceinline__ float sigm(float x) { return 1.f / (1.f + __expf(-x)); }

// Coherent (cross-XCD) h-state access: write-through stores / L2-bypassing loads.
__device__ __forceinline__ float bload(const float* p) {
    return __hip_atomic_load(p, __ATOMIC_RELAXED, __HIP_MEMORY_SCOPE_AGENT);
}
__device__ __forceinline__ void bstore(float* p, float v) {
    __hip_atomic_store(p, v, __ATOMIC_RELAXED, __HIP_MEMORY_SCOPE_AGENT);
}

// Two-level monotonic-epoch grid barrier. bar[g*32] = group counters (16),
// bar[GRP*32] = root counter, bar[GRP*32+32] = epoch broadcast. No cache
// maintenance anywhere — data crossing the barrier uses bload/bstore.
__device__ __forceinline__ void gbar(unsigned* bar, int wg, unsigned e) {
    __syncthreads();                      // drains each wave's vmcnt (h stores done)
    if (threadIdx.x == 0) {
        __builtin_amdgcn_s_waitcnt(0);
        const int g = wg / GSZ;
        unsigned old = __hip_atomic_fetch_add(&bar[g * 32], 1u,
                           __ATOMIC_RELAXED, __HIP_MEMORY_SCOPE_AGENT);
        if (old == e * GSZ - 1) {
            unsigned r = __hip_atomic_fetch_add(&bar[GRP * 32], 1u,
                             __ATOMIC_RELAXED, __HIP_MEMORY_SCOPE_AGENT);
            if (r == e * GRP - 1)
                __hip_atomic_store(&bar[GRP * 32 + 32], e,
                                   __ATOMIC_RELAXED, __HIP_MEMORY_SCOPE_AGENT);
        }
        while (__hip_atomic_load(&bar[GRP * 32 + 32],
                   __ATOMIC_RELAXED, __HIP_MEMORY_SCOPE_AGENT) < e)
            __builtin_amdgcn_s_sleep(1);
    }
    __syncthreads();
}

// 8 coherent h loads (consecutive k), lanes coalesced over b.
__device__ __forceinline__ void load8(const float* hsrc, int kbase, int b, float (&hv)[8]) {
#pragma unroll
    for (int u = 0; u < 8; ++u)
        hv[u] = bload(hsrc + (size_t)(kbase + u) * 64 + b);
}

// FMA block: 8 k-steps x ND d's x 4 gates; weights wave-uniform (scalar loads).
template <int ND, int KST>
__device__ __forceinline__ void fma8(const float* wbase, int kbase,
                                     const float (&hv)[8], float (&acc)[ND][4]) {
#pragma unroll
    for (int u = 0; u < 8; ++u) {
        const int k = kbase + u;
#pragma unroll
        for (int dd = 0; dd < ND; ++dd) {
            const float4 w4 = *(const float4*)(wbase + ((size_t)dd * KST + k) * 4);
            acc[dd][0] = fmaf(hv[u], w4.x, acc[dd][0]);
            acc[dd][1] = fmaf(hv[u], w4.y, acc[dd][1]);
            acc[dd][2] = fmaf(hv[u], w4.z, acc[dd][2]);
            acc[dd][3] = fmaf(hv[u], w4.w, acc[dd][3]);
        }
    }
}

// ---------------------------------------------------------------------------
// Weight prep (gate-interleaved, contiguous-k layouts):
//   W0t[d][k][g] = U0[k][g*640+d]                         (640 x 640 x 4)
//   Wc1[d][k][g] = (k<640 ? W1[k] : U1[k-640])[g*640+d]   (640 x 1280 x 4)
// ---------------------------------------------------------------------------
__global__ __launch_bounds__(256) void prep_weights(
    const float* __restrict__ U0, const float* __restrict__ W1,
    const float* __restrict__ U1, float* __restrict__ W0t,
    float* __restrict__ Wc1)
{
    int idx = blockIdx.x * 256 + threadIdx.x;
    if (idx < 640 * 640) {
        int d = idx / 640, k = idx % 640;
        const float* src = U0 + (size_t)k * L4_;
        float4 v;
        v.x = src[d]; v.y = src[640 + d]; v.z = src[1280 + d]; v.w = src[1920 + d];
        *(float4*)(W0t + (size_t)idx * 4) = v;
    }
    if (idx < 640 * 1280) {
        int d = idx / 1280, k = idx % 1280;
        const float* src = (k < 640) ? (W1 + (size_t)k * L4_)
                                     : (U1 + (size_t)(k - 640) * L4_);
        float4 v;
        v.x = src[d]; v.y = src[640 + d]; v.z = src[1280 + d]; v.w = src[1920 + d];
        *(float4*)(Wc1 + (size_t)idx * 4) = v;
    }
}

// ---------------------------------------------------------------------------
// GEMM0: xz[tl][n][b] = b0[n] + sum_k embed[targets[b][t0+tl]][k] * W0[k][n]
// ---------------------------------------------------------------------------
__global__ __launch_bounds__(256) void gemm_kernel(
    const float* __restrict__ A, const int* __restrict__ targets,
    const float* __restrict__ Wm, const float* __restrict__ bias,
    float* __restrict__ xz, int t0)
{
    const int tid = threadIdx.x;
    const int m0 = blockIdx.x * 128;
    const int n0 = blockIdx.y * 128;

    __shared__ float As[8][132];
    __shared__ float Bs[8][132];

    float acc[8][8];
#pragma unroll
    for (int i = 0; i < 8; ++i)
#pragma unroll
        for (int j = 0; j < 8; ++j) acc[i][j] = 0.f;

    const int a_ml = tid & 127;
    const int a_kq = (tid >> 7) * 4;
    {
        int m = m0 + a_ml;
        int b = m & 63;
        int tl = m >> 6;
        int idx = targets[b * U_ + t0 + tl];
        A += (size_t)idx * E_ + a_kq;
    }
    const int b_k  = tid >> 5;
    const int b_n4 = (tid & 31) * 4;
    const int tx = tid & 15;
    const int ty = tid >> 4;

    for (int k0 = 0; k0 < E_; k0 += 8) {
        float4 av = *(const float4*)(A + k0);
        As[a_kq + 0][a_ml] = av.x;
        As[a_kq + 1][a_ml] = av.y;
        As[a_kq + 2][a_ml] = av.z;
        As[a_kq + 3][a_ml] = av.w;
        float4 bv = *(const float4*)(Wm + (size_t)(k0 + b_k) * L4_ + n0 + b_n4);
        *(float4*)&Bs[b_k][b_n4] = bv;
        __syncthreads();

#pragma unroll
        for (int k = 0; k < 8; ++k) {
            float af[8], bf[8];
            *(float4*)&af[0] = *(const float4*)&As[k][ty * 8];
            *(float4*)&af[4] = *(const float4*)&As[k][ty * 8 + 4];
            *(float4*)&bf[0] = *(const float4*)&Bs[k][tx * 8];
            *(float4*)&bf[4] = *(const float4*)&Bs[k][tx * 8 + 4];
#pragma unroll
            for (int i = 0; i < 8; ++i)
#pragma unroll
                for (int j = 0; j < 8; ++j) acc[i][j] += af[i] * bf[j];
        }
        __syncthreads();
    }

#pragma unroll
    for (int i = 0; i < 8; ++i) {
        int m  = m0 + ty * 8 + i;
        int tl = m >> 6;
        int b  = m & 63;
        float* outp = xz + (size_t)tl * (L4_ * 64) + b;
#pragma unroll
        for (int j = 0; j < 8; ++j) {
            int n = n0 + tx * 8 + j;
            outp[(size_t)n * 64] = acc[i][j] + bias[n];
        }
    }
}

// ---------------------------------------------------------------------------
// Persistent per-chunk recurrence, custom barrier. 240 WGs x 512 threads.
//   WGs [0,80):   layer 0, 8 d's; iter i -> step t0+i   (i < TCc)
//   WGs [80,240): layer 1, 4 d's; iter i -> step t0+i-1 (i > 0)
// Write-once h slots: slot s (1..TCc) = h[t0+s-1]; slot TCc = carry-in.
// h crossing WGs: bstore/bload (coherent). Weights/xz: normal cached loads.
// ---------------------------------------------------------------------------
__global__ __launch_bounds__(512) void recur_chunk(
    const float* __restrict__ xz,     // [TCc][2560][64]
    const float* __restrict__ W0t,    // [640][640][4]
    const float* __restrict__ Wc1,    // [640][1280][4]
    const float* __restrict__ b1,     // [2560]
    const int*   __restrict__ lens,   // [64]
    float* __restrict__ h0s,          // [TCc+1][640][64]
    float* __restrict__ h1s,          // [TCc+1][640][64]
    float* __restrict__ c0g,          // [640*64]
    float* __restrict__ c1g,          // [640*64]
    unsigned* bar, int epoch_base, int t0, int TCc)
{
    __shared__ float red[8][4][8][64];   // [didx][gate][wave][b] 64 KiB
    const int wg  = blockIdx.x;
    const int tid = threadIdx.x;
    const int b   = tid & 63;
    const int wv  = tid >> 6;            // wave 0..7
    const int len_b = lens[b];

    if (wg < 80) {
        // ----------------------------- layer 0 -----------------------------
        const int d0   = wg * 8;
        const int didx = tid >> 6;       // all 512 threads own (od, b)
        const int od   = d0 + didx;
        float c_r = c0g[od * 64 + b];
        float h_r = h0s[(size_t)SLOT * TCc + od * 64 + b];
        const float* wbase = W0t + (size_t)d0 * 2560;
        const int k0 = wv * 80;

        for (int i = 0; i <= TCc; ++i) {
            if (i < TCc) {
                const float* hsrc = h0s + (size_t)SLOT * (i == 0 ? TCc : i);
                float acc[8][4] = {};
                float hva[8], hvb[8];
                load8(hsrc, k0, b, hva);
#pragma unroll 1
                for (int jb = 0; jb < 80; jb += 16) {
                    load8(hsrc, k0 + jb + 8, b, hvb);
                    fma8<8, 640>(wbase, k0 + jb, hva, acc);
                    if (jb + 16 < 80) load8(hsrc, k0 + jb + 16, b, hva);
                    fma8<8, 640>(wbase, k0 + jb + 8, hvb, acc);
                }
#pragma unroll
                for (int dd = 0; dd < 8; ++dd)
#pragma unroll
                    for (int g = 0; g < 4; ++g) red[dd][g][wv][b] = acc[dd][g];
                __syncthreads();
                {
                    float z[4];
#pragma unroll
                    for (int g = 0; g < 4; ++g) {
                        float s = 0.f;
#pragma unroll
                        for (int w2 = 0; w2 < 8; ++w2) s += red[didx][g][w2][b];
                        z[g] = s + xz[((size_t)i * L4_ + g * 640 + od) * 64 + b];
                    }
                    float ig = sigm(z[0]), fg = sigm(z[1]);
                    float gg = tanhf(z[2]), og = sigm(z[3]);
                    float cn = fg * c_r + ig * gg;
                    float hn = og * tanhf(cn);
                    bool  m  = (t0 + i) < len_b;
                    h_r = m ? hn : h_r;
                    c_r = m ? cn : c_r;
                    bstore(h0s + (size_t)SLOT * (i + 1) + od * 64 + b, h_r);
                }
            }
            gbar(bar, wg, (unsigned)(epoch_base + i + 1));
        }
        c0g[od * 64 + b] = c_r;
    } else {
        // ----------------------------- layer 1 -----------------------------
        const int d0   = (wg - 80) * 4;
        const int didx = tid >> 6;
        const int od   = d0 + (didx & 3);     // owners: tid < 256
        float c_r = c1g[od * 64 + b];
        float h_r = h1s[(size_t)SLOT * TCc + od * 64 + b];
        const float* wbase = Wc1 + (size_t)d0 * 5120;
        const int kg0 = wv * 160;             // global k in [0,1280)

        for (int i = 0; i <= TCc; ++i) {
            if (i > 0) {
                const float* h0slot = h0s + (size_t)SLOT * i;                 // h0[t0+i-1]
                const float* h1slot = h1s + (size_t)SLOT * (i == 1 ? TCc : (i - 1)); // h1[t0+i-2]
                const float* hsrc = (wv < 4) ? h0slot : (h1slot - (size_t)640 * 64);
                float acc[4][4] = {};
                float hva[8], hvb[8];
                load8(hsrc, kg0, b, hva);
#pragma unroll 1
                for (int jb = 0; jb < 160; jb += 16) {
                    load8(hsrc, kg0 + jb + 8, b, hvb);
                    fma8<4, 1280>(wbase, kg0 + jb, hva, acc);
                    if (jb + 16 < 160) load8(hsrc, kg0 + jb + 16, b, hva);
                    fma8<4, 1280>(wbase, kg0 + jb + 8, hvb, acc);
                }
#pragma unroll
                for (int dd = 0; dd < 4; ++dd)
#pragma unroll
                    for (int g = 0; g < 4; ++g) red[dd][g][wv][b] = acc[dd][g];
                __syncthreads();
                if (tid < 256) {
                    float z[4];
#pragma unroll
                    for (int g = 0; g < 4; ++g) {
                        float s = 0.f;
#pragma unroll
                        for (int w2 = 0; w2 < 8; ++w2) s += red[didx][g][w2][b];
                        z[g] = s + b1[g * 640 + od];
                    }
                    float ig = sigm(z[0]), fg = sigm(z[1]);
                    float gg = tanhf(z[2]), og = sigm(z[3]);
                    float cn = fg * c_r + ig * gg;
                    float hn = og * tanhf(cn);
                    bool  m  = (t0 + i - 1) < len_b;
                    h_r = m ? hn : h_r;
                    c_r = m ? cn : c_r;
                    bstore(h1s + (size_t)SLOT * i + od * 64 + b, h_r);
                }
            }
            gbar(bar, wg, (unsigned)(epoch_base + i + 1));
        }
        if (tid < 256) c1g[od * 64 + b] = c_r;
    }
}

// ---------------------------------------------------------------------------
// Transpose chunk: h1s slot tl+1 ([d][b]) -> out[b][t0+tl][d]
// ---------------------------------------------------------------------------
__global__ __launch_bounds__(256) void transpose_kernel(
    const float* __restrict__ h1s, float* __restrict__ out, int t0)
{
    const int tl   = blockIdx.x;
    const int dblk = blockIdx.y;
    __shared__ float tile[64][65];

    const int r  = threadIdx.x >> 2;
    const int cq = threadIdx.x & 3;

    const float* src = h1s + (size_t)SLOT * (tl + 1)
                     + (size_t)(dblk * 64 + r) * 64 + cq * 16;
#pragma unroll
    for (int j = 0; j < 4; ++j) {
        float4 vv = *(const float4*)(src + j * 4);
        tile[r][cq * 16 + j * 4 + 0] = vv.x;
        tile[r][cq * 16 + j * 4 + 1] = vv.y;
        tile[r][cq * 16 + j * 4 + 2] = vv.z;
        tile[r][cq * 16 + j * 4 + 3] = vv.w;
    }
    __syncthreads();

    float* dst = out + (size_t)r * (U_ * D_) + (size_t)(t0 + tl) * D_ + dblk * 64 + cq * 16;
#pragma unroll
    for (int j = 0; j < 4; ++j) {
        float4 ww;
        ww.x = tile[cq * 16 + j * 4 + 0][r];
        ww.y = tile[cq * 16 + j * 4 + 1][r];
        ww.z = tile[cq * 16 + j * 4 + 2][r];
        ww.w = tile[cq * 16 + j * 4 + 3][r];
        *(float4*)(dst + j * 4) = ww;
    }
}

// ---------------------------------------------------------------------------
extern "C" void kernel_launch(void* const* d_in, const int* in_sizes, int n_in,
                              void* d_out, int out_size, void* d_ws, size_t ws_size,
                              hipStream_t stream)
{
    const int*   targets = (const int*)d_in[0];
    const int*   lens    = (const int*)d_in[1];
    const float* embed   = (const float*)d_in[2];
    const float* W0      = (const float*)d_in[3];
    const float* U0      = (const float*)d_in[4];
    const float* b0      = (const float*)d_in[5];
    const float* W1      = (const float*)d_in[6];
    const float* U1      = (const float*)d_in[7];
    const float* b1      = (const float*)d_in[8];
    float* out = (float*)d_out;
    float* ws  = (float*)d_ws;

    // need(TC) = 4*(TC*163840 + 4,915,200 + 2*(TC+1)*40960 + 81,920) + 4096
    const int TCc = (ws_size >= (size_t)83234816) ? 64 : 32;
    const int NCH = U_ / TCc;

    float* xz  = ws;                                        // TCc*2560*64
    float* W0t = xz  + (size_t)TCc * L4_ * 64;              // 1,638,400
    float* Wc1 = W0t + (size_t)640 * 640 * 4;               // 3,276,800
    float* h0s = Wc1 + (size_t)640 * 1280 * 4;              // (TCc+1)*SLOT
    float* h1s = h0s + (size_t)(TCc + 1) * SLOT;            // (TCc+1)*SLOT
    float* c0g = h1s + (size_t)(TCc + 1) * SLOT;            // SLOT
    float* c1g = c0g + SLOT;                                // SLOT
    unsigned* bar = (unsigned*)(c1g + SLOT);                // 4 KiB

    // zero carry-in slots, c-state, and barrier counters
    hipMemsetAsync(h0s + (size_t)SLOT * TCc, 0, (size_t)SLOT * 4, stream);
    hipMemsetAsync(h1s + (size_t)SLOT * TCc, 0, (size_t)SLOT * 4, stream);
    hipMemsetAsync(c0g, 0, (size_t)2 * SLOT * 4 + 4096, stream);

    prep_weights<<<dim3(3200), dim3(256), 0, stream>>>(U0, W1, U1, W0t, Wc1);

    for (int ch = 0; ch < NCH; ++ch) {
        const int t0 = ch * TCc;

        gemm_kernel<<<dim3(TCc * 64 / 128, L4_ / 128), dim3(256), 0, stream>>>(
            embed, targets, W0, b0, xz, t0);

        int t0v = t0, TCv = TCc, ebase = ch * (TCc + 1);
        void* args[] = { (void*)&xz, (void*)&W0t, (void*)&Wc1, (void*)&b1,
                         (void*)&lens, (void*)&h0s, (void*)&h1s,
                         (void*)&c0g, (void*)&c1g, (void*)&bar,
                         (void*)&ebase, (void*)&t0v, (void*)&TCv };
        hipLaunchCooperativeKernel((void*)recur_chunk, dim3(RWG), dim3(512),
                                   args, 0, stream);

        transpose_kernel<<<dim3(TCc, 10), dim3(256), 0, stream>>>(h1s, out, t0);
    }
}